// Round 4
// baseline (245.216 us; speedup 1.0000x reference)
//
#include <hip/hip_runtime.h>
#include <hip/hip_fp16.h>
#include <stdint.h>

// Problem dims (fixed by reference)
// Reference dtypes: x fp16, bias fp16, out fp16 -> harness passes/reads FLOAT32.
// packed_w int32 (8192 x 512), 16 two-bit codes per word, values {0,1,3}.
#define M_DIM 1024
#define N_DIM 8192
#define K_DIM 8192
#define KP    (K_DIM / 16)   // 512 packed int32 words per weight row

#define BM 128
#define BN 128
#define BK 64
#define NTHREADS 256
#define B_STRIDE 144          // fallback kernel only

// Transposed A workspace layout (bytes), built by cvt_x_t:
//   mt(8):2 MiB | kt(128):16 KiB | i32(4):4 KiB | ks(4):1 KiB | q(2):512 | r(32):16
// A-fragment (i32, ks) = contiguous 1 KB at base + lane*16 (lane = q*32+r).
#define MT_STRIDE 2097152
#define KT_STRIDE 16384

typedef _Float16 half8   __attribute__((ext_vector_type(8)));
typedef __fp16   fp16x2  __attribute__((ext_vector_type(2)));
typedef float    f32x4   __attribute__((ext_vector_type(4)));
typedef float    f32x16  __attribute__((ext_vector_type(16)));

__device__ __forceinline__ uint32_t cvt2(float a, float b) {
  fp16x2 p = __builtin_amdgcn_cvt_pkrtz(a, b);   // RTZ exact: values are fp16-representable
  return __builtin_bit_cast(uint32_t, p);
}

// Async global->LDS 16B copy. LDS dest is wave-uniform base + lane*16 (HW rule),
// so the LDS base passed here must be wave-uniform and the global ptr per-lane.
__device__ __forceinline__ void gload_lds16(const char* g, char* l) {
  __builtin_amdgcn_global_load_lds(
      (const __attribute__((address_space(1))) void*)g,
      (__attribute__((address_space(3))) void*)l, 16, 0, 0);
}

// ---- consumer-side half-word ternary decode (verified R8) ----
// word = 16 codes; quad half (sh = quad*16) = 8 codes -> half8 MFMA B-fragment.
// T byte-table [0x00,0x3C,0x06,0x42] = fp16 hi-bytes of {0,1,2,3} (low byte always 0).
__device__ __forceinline__ half8 dec_frag(uint32_t word, uint32_t sh) {
  const uint32_t T = 0x42063C00u;
  uint32_t h  = (word >> sh) & 0xFFFFu;
  uint32_t W  = (h & 0x3333u) | ((h << 14) & 0x33330000u);
  uint32_t c0 = __builtin_amdgcn_perm(0u, W, 0x04040200u);  // W.b0 | W.b2<<8
  uint32_t c1 = __builtin_amdgcn_perm(0u, W, 0x04040301u);  // W.b1 | W.b3<<8
  uint32_t s0 = (c0 * 0x1001u) & 0x03030303u;               // [c0,c1,c2,c3]
  uint32_t s1 = (c1 * 0x1001u) & 0x03030303u;               // [c4,c5,c6,c7]
  uint32_t P0 = __builtin_amdgcn_perm(0u, T, s0);
  uint32_t P1 = __builtin_amdgcn_perm(0u, T, s1);
  uint4 v;
  v.x = __builtin_amdgcn_perm(P0, 0u, 0x05000400u);  // fp16(c0), fp16(c1)
  v.y = __builtin_amdgcn_perm(P0, 0u, 0x07000600u);  // fp16(c2), fp16(c3)
  v.z = __builtin_amdgcn_perm(P1, 0u, 0x05000400u);  // fp16(c4), fp16(c5)
  v.w = __builtin_amdgcn_perm(P1, 0u, 0x07000600u);  // fp16(c6), fp16(c7)
  return __builtin_bit_cast(half8, v);
}

// ---- pre-pass: x f32 -> fp16, transposed-tiled into workspace (R8, verified) ----
__global__ __launch_bounds__(256)
void cvt_x_t(const float* __restrict__ x, char* __restrict__ xhT) {
  __shared__ __align__(16) char st[16384];
  const int b  = blockIdx.x;
  const int mt = b >> 7, kt = b & 127;
  const int t  = threadIdx.x;
#pragma unroll
  for (int p = 0; p < 8; ++p) {
    int f   = t + 256 * p;
    int R   = f >> 4;
    int cc4 = f & 15;
    float4 v = *(const float4*)(x + (size_t)(mt * 128 + R) * K_DIM + kt * 64 + cc4 * 4);
    uint32_t w0 = cvt2(v.x, v.y), w1 = cvt2(v.z, v.w);
    int c8 = cc4 >> 1, hh = cc4 & 1;
    int i32 = R >> 5, r = R & 31, ks = c8 >> 1, q = c8 & 1;
    *(uint2*)(st + i32 * 4096 + ks * 1024 + q * 512 + r * 16 + hh * 8) = make_uint2(w0, w1);
  }
  __syncthreads();
  char* outb = xhT + (size_t)mt * MT_STRIDE + (size_t)kt * KT_STRIDE;
#pragma unroll
  for (int e = 0; e < 4; ++e) {
    int d = (e * 256 + t) * 16;
    *(uint4*)(outb + d) = *(const uint4*)(st + d);
  }
}

// ====== fast path ======
// R12: R11 skeleton (LDS-A 3-deep via global_load_lds, counted vmcnt barriers,
// m2n2 wave tile) with two changes targeting pipe OVERLAP (R11: MFMA 40% +
// VALU 49% summed, not overlapped — waves phase-aligned on the step-start
// lgkm-dependent decode chain):
//   1. B-words: per-lane direct global dwordx4, register double-buffered one
//      step ahead. Decode now starts from registers at step entry — zero LDS
//      dependency. Consecutive steps walk the same 64B line (3/4 L1 hits).
//      In-flight VMEM/step = 2 B + 4 gload_lds -> vmcnt(6); B issued first so
//      the compiler's auto-wait for B next step is vmcnt(4), A-stage keeps flying.
//   2. Role split + T5: step = [issue loads | decode 8 frags (pure-reg VALU) |
//      setprio(1) 16-MFMA cluster setprio(0) | counted barrier]. Co-resident
//      waves are from different blocks (free-running): setprio arbitrates
//      {decode-wave vs MFMA-wave} into anti-phase (m224 condition).
__global__ __launch_bounds__(NTHREADS, 2)
void ternary_gemm_dc(const char* __restrict__ xhT,
                     const int*  __restrict__ pw,
                     const float* __restrict__ bias,
                     float*       __restrict__ out) {
  __shared__ __align__(16) char Ast[3 * 16384];  // A fp16 tiles, 3-deep (verbatim ws layout)

  const int tid  = threadIdx.x;
  const int lane = tid & 63;
  const int w    = tid >> 6;
  const int wm   = w >> 1, wn = w & 1;
  const int bid  = blockIdx.x;
  const int mt   = bid & 7;           // XCD swizzle: one 2 MiB A-slab per XCD hot in L2
  const int bm   = mt * BM;
  const int bn   = (bid >> 3) * BN;

  // A staging: wave w copies 4 KB chunk w: 4 insts of 16B/lane, linear.
  const char* gAs = xhT + (size_t)mt * MT_STRIDE + w * 4096 + lane * 16;  // + e*1024 + kt*KT

  // B: per-lane direct pointers. Row j covers W-row wn*64 + j*32 + (lane&31);
  // uint4 index kt = words kt*4..kt*4+3 (one BK=64 K-step). Row stride 2048 B.
  const uint4* pB0 = (const uint4*)pw + (size_t)(bn + wn * 64 + (lane & 31)) * (KP / 4);
  const uint4* pB1 = pB0 + 32 * (KP / 4);
  const uint32_t sh = (lane >> 5) * 16;   // quad selects codes 0-7 vs 8-15 of each word

  // A fragment read base: buf/i/ks folded into ds_read immediate offsets
  const char* const aPtr = Ast + wm * 8192 + lane * 16;  // + buf*16384 + i*4096 + ks*1024

  f32x16 acc[2][2];
#pragma unroll
  for (int i = 0; i < 2; ++i)
#pragma unroll
    for (int j = 0; j < 2; ++j) acc[i][j] = (f32x16)(0.f);

  const int NT = K_DIM / BK;   // 128

  auto stageA = [&](int buf, int kt) {
    const char* g = gAs + (size_t)kt * KT_STRIDE;
    char* lbase = Ast + buf * 16384 + w * 4096;   // wave-uniform LDS base
#pragma unroll
    for (int e = 0; e < 4; ++e)
      gload_lds16(g + e * 1024, lbase + e * 1024);
  };

  // ---- prologue: A(0)->buf0, A(1)->buf1 (async); B words(0) -> regs ----
  stageA(0, 0);
  stageA(1, 1);
  uint4 cA0 = pB0[0], cA1 = pB1[0];
  uint4 cB0, cB1;
  __syncthreads();                   // full drain ONCE: A0,A1 + B0 ready

  // step: cur / reg-sets literal at every call site -> offsets fold.
  auto step = [&](int cur, int kt, uint4& c0, uint4& c1, uint4& n0, uint4& n1,
                  bool counted) {
    // Issue B(kt+1) loads FIRST (oldest VMEM this step), then A-stage(kt+2).
    int knb = (kt + 1 < NT) ? kt + 1 : NT - 1;
    n0 = pB0[knb];
    n1 = pB1[knb];
    if (kt + 2 < NT) stageA((kt + 2) % 3, kt + 2);

    // A frags: 8 ds_read_b128, issued before decode so latency hides under it.
    half8 a0[4], a1[4];
#pragma unroll
    for (int ks = 0; ks < 4; ++ks) {
      a0[ks] = *(const half8*)(aPtr + cur * 16384 + 0 * 4096 + ks * 1024);
      a1[ks] = *(const half8*)(aPtr + cur * 16384 + 1 * 4096 + ks * 1024);
    }

    // Decode all 8 B-fragments from registers (no memory dependency).
    uint32_t wd0[4] = {c0.x, c0.y, c0.z, c0.w};
    uint32_t wd1[4] = {c1.x, c1.y, c1.z, c1.w};
    half8 bf0[4], bf1[4];
#pragma unroll
    for (int ks = 0; ks < 4; ++ks) {
      bf0[ks] = dec_frag(wd0[ks], sh);
      bf1[ks] = dec_frag(wd1[ks], sh);
    }

    // MFMA cluster under raised priority (T5): 4 independent chains x 4 deep.
    __builtin_amdgcn_s_setprio(1);
#pragma unroll
    for (int ks = 0; ks < 4; ++ks) {
      acc[0][0] = __builtin_amdgcn_mfma_f32_32x32x16_f16(a0[ks], bf0[ks], acc[0][0], 0, 0, 0);
      acc[0][1] = __builtin_amdgcn_mfma_f32_32x32x16_f16(a0[ks], bf1[ks], acc[0][1], 0, 0, 0);
      acc[1][0] = __builtin_amdgcn_mfma_f32_32x32x16_f16(a1[ks], bf0[ks], acc[1][0], 0, 0, 0);
      acc[1][1] = __builtin_amdgcn_mfma_f32_32x32x16_f16(a1[ks], bf1[ks], acc[1][1], 0, 0, 0);
    }
    __builtin_amdgcn_s_setprio(0);

    if (counted) {
      // T4: keep this step's 6 VMEM ops (2 B + 4 gload_lds) in flight across
      // the barrier; everything older (stage kt+1, B kt) is forced complete.
      __builtin_amdgcn_sched_barrier(0);
      asm volatile("s_waitcnt vmcnt(6) lgkmcnt(0)" ::: "memory");
      __builtin_amdgcn_s_barrier();
      asm volatile("" ::: "memory");
      __builtin_amdgcn_sched_barrier(0);
    } else {
      __syncthreads();
    }
  };

  // Main loop: buffer index = kt % 3, B reg-set alternates per step -> LCM 6.
  for (int kt = 0; kt < NT - 2; kt += 6) {   // 126 = 6 * 21 steps
    step(0, kt,     cA0, cA1, cB0, cB1, true);
    step(1, kt + 1, cB0, cB1, cA0, cA1, true);
    step(2, kt + 2, cA0, cA1, cB0, cB1, true);
    step(0, kt + 3, cB0, cB1, cA0, cA1, true);
    step(1, kt + 4, cA0, cA1, cB0, cB1, true);
    step(2, kt + 5, cB0, cB1, cA0, cA1, true);
  }
  step(0, NT - 2, cA0, cA1, cB0, cB1, false);   // tails: full drains
  step(1, NT - 1, cB0, cB1, cA0, cA1, false);

  // Epilogue: 32x32 C/D (m74/m101): col(n)=lane&31, row(m)=(reg&3)+8*(reg>>2)+4*(lane>>5)
  // fp16 rounding replicated exactly: f16(y) + f16(bias) in half, widen to f32.
#pragma unroll
  for (int j = 0; j < 2; ++j) {
    int n = bn + wn * 64 + j * 32 + (lane & 31);
    __half hb = __float2half_rn(bias[n]);
#pragma unroll
    for (int i = 0; i < 2; ++i) {
      int mbase = bm + wm * 64 + i * 32 + 4 * (lane >> 5);
#pragma unroll
      for (int reg = 0; reg < 16; ++reg) {
        int m = mbase + (reg & 3) + 8 * (reg >> 2);
        __half hy = __float2half_rn(acc[i][j][reg]);
        out[(size_t)m * N_DIM + n] = __half2float(__hadd(hy, hb));
      }
    }
  }
}

// ================= fallback (R4 kernel, known-good): used only if ws too small =================
__device__ __forceinline__ uint32_t unpack_pair16(uint32_t u, int p) {
  uint32_t c0 = (u >> (4 * p)) & 3u;
  uint32_t c1 = (u >> (4 * p + 2)) & 3u;
  uint32_t lo = (c0 & 1u) * 0x3C00u + (c0 >> 1) * 0x0600u;
  uint32_t hi = (c1 & 1u) * 0x3C00u + (c1 >> 1) * 0x0600u;
  return lo | (hi << 16);
}

__global__ __launch_bounds__(NTHREADS, 2)
void ternary_gemm(const float* __restrict__ x,
                  const int*   __restrict__ pw,
                  const float* __restrict__ bias,
                  float*       __restrict__ out) {
  __shared__ __align__(16) char AsB[128 * B_STRIDE];
  __shared__ __align__(16) char BsB[128 * B_STRIDE];

  const int tid  = threadIdx.x;
  const int lane = tid & 63;
  const int w    = tid >> 6;
  const int wm   = w >> 1, wn = w & 1;
  const int bid  = blockIdx.x;
  const int bm   = (bid & 7) * 128;
  const int bn   = (bid >> 3) * 128;

  const int rT = tid >> 1, hT = tid & 1;
  const float* gA = x + (size_t)(bm + rT) * K_DIM + hT * 32;
  char* const  lA = AsB + rT * B_STRIDE + hT * 64;
  const int2* gB = (const int2*)pw + (size_t)(bn + rT) * (KP / 2) + hT;
  char* dBp[4];
#pragma unroll
  for (int h = 0; h < 4; ++h)
    dBp[h] = BsB + rT * B_STRIDE + (hT * 4 + h) * 16;

  int offA[4][2], offB[4][2];
#pragma unroll
  for (int i = 0; i < 4; ++i)
#pragma unroll
    for (int ks = 0; ks < 2; ++ks) {
      int c = ks * 4 + (lane >> 4);
      offA[i][ks] = (wm * 64 + i * 16 + (lane & 15)) * B_STRIDE + c * 16;
      offB[i][ks] = (wn * 64 + i * 16 + (lane & 15)) * B_STRIDE + c * 16;
    }

  f32x4 acc[4][4];
#pragma unroll
  for (int i = 0; i < 4; ++i)
#pragma unroll
    for (int j = 0; j < 4; ++j)
      acc[i][j] = (f32x4){0.f, 0.f, 0.f, 0.f};

  const int NT = K_DIM / BK;
  for (int kt = 0; kt < NT; ++kt) {
    __syncthreads();
    int2 wcur = gB[kt * 2];
    float4 av[8];
#pragma unroll
    for (int v = 0; v < 8; ++v) av[v] = *(const float4*)(gA + kt * BK + v * 4);
    uint32_t d0[8], d1[8];
#pragma unroll
    for (int p = 0; p < 8; ++p) d0[p] = unpack_pair16((uint32_t)wcur.x, p);
#pragma unroll
    for (int p = 0; p < 8; ++p) d1[p] = unpack_pair16((uint32_t)wcur.y, p);
    *(uint4*)dBp[0] = make_uint4(d0[0], d0[1], d0[2], d0[3]);
    *(uint4*)dBp[1] = make_uint4(d0[4], d0[5], d0[6], d0[7]);
    *(uint4*)dBp[2] = make_uint4(d1[0], d1[1], d1[2], d1[3]);
    *(uint4*)dBp[3] = make_uint4(d1[4], d1[5], d1[6], d1[7]);
#pragma unroll
    for (int v = 0; v < 4; ++v) {
      uint4 aw;
      aw.x = cvt2(av[2 * v].x, av[2 * v].y);
      aw.y = cvt2(av[2 * v].z, av[2 * v].w);
      aw.z = cvt2(av[2 * v + 1].x, av[2 * v + 1].y);
      aw.w = cvt2(av[2 * v + 1].z, av[2 * v + 1].w);
      *(uint4*)(lA + v * 16) = aw;
    }
    __syncthreads();
#pragma unroll
    for (int ks = 0; ks < 2; ++ks) {
      half8 af[4], bf[4];
#pragma unroll
      for (int i = 0; i < 4; ++i) af[i] = *(const half8*)(AsB + offA[i][ks]);
#pragma unroll
      for (int j = 0; j < 4; ++j) bf[j] = *(const half8*)(BsB + offB[j][ks]);
#pragma unroll
      for (int i = 0; i < 4; ++i)
#pragma unroll
        for (int j = 0; j < 4; ++j)
          acc[i][j] = __builtin_amdgcn_mfma_f32_16x16x32_f16(af[i], bf[j], acc[i][j], 0, 0, 0);
    }
  }
#pragma unroll
  for (int j = 0; j < 4; ++j) {
    int n = bn + wn * 64 + j * 16 + (lane & 15);
    __half hb = __float2half_rn(bias[n]);
#pragma unroll
    for (int i = 0; i < 4; ++i) {
      int m0 = bm + wm * 64 + i * 16 + (lane >> 4) * 4;
#pragma unroll
      for (int r = 0; r < 4; ++r) {
        __half hy = __float2half_rn(acc[i][j][r]);
        out[(size_t)(m0 + r) * N_DIM + n] = __half2float(__hadd(hy, hb));
      }
    }
  }
}

extern "C" void kernel_launch(void* const* d_in, const int* in_sizes, int n_in,
                              void* d_out, int out_size, void* d_ws, size_t ws_size,
                              hipStream_t stream) {
  (void)in_sizes; (void)n_in; (void)out_size;
  const float* x    = (const float*)d_in[0];
  const int*   pwp  = (const int*)d_in[1];
  const float* bias = (const float*)d_in[2];
  float*       outp = (float*)d_out;

  const size_t need = (size_t)M_DIM * K_DIM * 2;   // 16 MiB fp16 x (transposed)
  if (ws_size >= need) {
    char* xhT = (char*)d_ws;
    cvt_x_t<<<8 * 128, 256, 0, stream>>>(x, xhT);
    dim3 grid((M_DIM / BM) * (N_DIM / BN));        // 512 blocks
    ternary_gemm_dc<<<grid, NTHREADS, 0, stream>>>(xhT, pwp, bias, outp);
  } else {
    dim3 grid((M_DIM / 128) * (N_DIM / 128));      // 512 blocks
    ternary_gemm<<<grid, NTHREADS, 0, stream>>>(x, pwp, bias, outp);
  }
}